// Round 7
// baseline (461.609 us; speedup 1.0000x reference)
//
#include <hip/hip_runtime.h>
#include <hip/hip_bf16.h>
#include <math.h>

#define DIM 128

typedef __bf16 bf8 __attribute__((ext_vector_type(8)));
typedef float f4 __attribute__((ext_vector_type(4)));

struct __align__(8) bf16x4 { __hip_bfloat162 a, b; };

// ---- merged prep: sigmoid(rel)->bf16, Wcat bf16, W_rel^T, zero offs ----
__global__ __launch_bounds__(256) void prep_kernel(
    const float* __restrict__ rel,
    const float* __restrict__ Ws,
    const float* __restrict__ Wn,
    const float* __restrict__ Wr,
    __hip_bfloat16* __restrict__ sigb,
    __hip_bfloat16* __restrict__ Wcat,
    float* __restrict__ Wt_rel,
    int* __restrict__ offs,
    int nSig, int sigBlocks, int N) {
    int b = blockIdx.x;
    if (b < sigBlocks) {
        int i = b * 256 + threadIdx.x;
        if (i < nSig) {
            float x = rel[i];
            sigb[i] = __float2bfloat16(1.0f / (1.0f + expf(-x)));
        }
    } else if (b < sigBlocks + 32) {
        int idx = (b - sigBlocks) * 256 + threadIdx.x;   // 0..8191, 4 elems each
        int j  = idx >> 6;
        int k0 = (idx & 63) * 4;
        const float* src = (k0 < DIM) ? &Ws[j * DIM + k0] : &Wn[j * DIM + (k0 - DIM)];
        float4 v = *(const float4*)src;
        bf16x4 o;
        o.a.x = __float2bfloat16(v.x);
        o.a.y = __float2bfloat16(v.y);
        o.b.x = __float2bfloat16(v.z);
        o.b.y = __float2bfloat16(v.w);
        *(bf16x4*)&Wcat[(size_t)j * 256 + k0] = o;
    } else if (b < sigBlocks + 32 + 64) {
        int id = (b - sigBlocks - 32) * 256 + threadIdx.x;  // 0..16383
        int k = id >> 7;
        int j = id & 127;
        Wt_rel[id] = Wr[j * DIM + k];
    } else {
        int i = (b - sigBlocks - 32 - 64) * 256 + threadIdx.x;
        if (i <= N) offs[i] = 0;
    }
}

// ---- merged: ent fp32 -> xcat bf16 (cols 0..127)  +  dst histogram ----
__global__ __launch_bounds__(256) void conv_hist_kernel(
    const float* __restrict__ ent,
    __hip_bfloat16* __restrict__ xcat,
    const int* __restrict__ edge_index,
    int* __restrict__ counts,
    int N, int E, int convBlocks) {
    if ((int)blockIdx.x < convBlocks) {
        long long tid = (long long)blockIdx.x * 256 + threadIdx.x;
        int row = (int)(tid >> 5);
        int q   = (int)(tid & 31);
        if (row >= N) return;
        float4 v = *(const float4*)&ent[(size_t)row * DIM + q * 4];
        bf16x4 o;
        o.a.x = __float2bfloat16(v.x);
        o.a.y = __float2bfloat16(v.y);
        o.b.x = __float2bfloat16(v.z);
        o.b.y = __float2bfloat16(v.w);
        *(bf16x4*)&xcat[(size_t)row * 256 + q * 4] = o;
    } else {
        int e = (blockIdx.x - convBlocks) * 256 + threadIdx.x;
        if (e < E) atomicAdd(&counts[edge_index[E + e]], 1);
    }
}

// ---- single-block exclusive scan over N counts (in-place), inits cursor ----
#define SCB_T 1024
__global__ __launch_bounds__(1024) void scan_all_kernel(
    int* __restrict__ offs, int* __restrict__ cursor, int N, int E) {
    __shared__ int ts[SCB_T];
    int t = threadIdx.x;
    const int C = (N + SCB_T - 1) / SCB_T;
    int lo = t * C;
    int hi = lo + C; if (hi > N) hi = N; if (lo > N) lo = N;
    int s = 0;
    for (int i = lo; i < hi; ++i) s += offs[i];
    ts[t] = s;
    __syncthreads();
    for (int off = 1; off < SCB_T; off <<= 1) {
        int x = (t >= off) ? ts[t - off] : 0;
        __syncthreads();
        ts[t] += x;
        __syncthreads();
    }
    int run = ts[t] - s;   // exclusive prefix of this chunk
    for (int i = lo; i < hi; ++i) {
        int v = offs[i];
        offs[i] = run;
        cursor[i] = run;
        run += v;
    }
    if (t == 0) offs[N] = E;
}

// ---- scatter packed (src | type<<17) into CSR order ----
__global__ void scatter_ids_kernel(const int* __restrict__ edge_index,
                                   const int* __restrict__ edge_type,
                                   int* __restrict__ cursor,
                                   unsigned* __restrict__ spack, int E) {
    int e = blockIdx.x * blockDim.x + threadIdx.x;
    if (e >= E) return;
    int dst = edge_index[E + e];
    int p = atomicAdd(&cursor[dst], 1);
    spack[p] = (unsigned)edge_index[e] | ((unsigned)edge_type[e] << 17);
}

// ---- atomic-free aggregation: 1 wave / node, fully-predicated 4-wide batches ----
__global__ __launch_bounds__(256) void aggregate_kernel(
    const __hip_bfloat16* __restrict__ xcat,
    const __hip_bfloat16* __restrict__ sigb,
    const int* __restrict__ offs,
    const unsigned* __restrict__ spack,
    __hip_bfloat16* __restrict__ xcat_w, int N) {
    int wid  = (int)((blockIdx.x * (long long)blockDim.x + threadIdx.x) >> 6);
    int lane = threadIdx.x & 63;
    if (wid >= N) return;
    int beg = offs[wid], end = offs[wid + 1];
    float ax0 = 0.f, ay0 = 0.f, ax1 = 0.f, ay1 = 0.f;
    for (int e = beg; e < end; e += 4) {
        int r = end - e;                       // >= 1
        unsigned p0 = spack[e];
        unsigned p1 = spack[r > 1 ? e + 1 : e];
        unsigned p2 = spack[r > 2 ? e + 2 : e];
        unsigned p3 = spack[r > 3 ? e + 3 : e];
        __hip_bfloat162 v0 = *(const __hip_bfloat162*)&xcat[(size_t)(p0 & 0x1FFFFu) * 256 + lane * 2];
        __hip_bfloat162 v1 = *(const __hip_bfloat162*)&xcat[(size_t)(p1 & 0x1FFFFu) * 256 + lane * 2];
        __hip_bfloat162 v2 = *(const __hip_bfloat162*)&xcat[(size_t)(p2 & 0x1FFFFu) * 256 + lane * 2];
        __hip_bfloat162 v3 = *(const __hip_bfloat162*)&xcat[(size_t)(p3 & 0x1FFFFu) * 256 + lane * 2];
        __hip_bfloat162 g0 = *(const __hip_bfloat162*)&sigb[(size_t)(p0 >> 17) * DIM + lane * 2];
        __hip_bfloat162 g1 = *(const __hip_bfloat162*)&sigb[(size_t)(p1 >> 17) * DIM + lane * 2];
        __hip_bfloat162 g2 = *(const __hip_bfloat162*)&sigb[(size_t)(p2 >> 17) * DIM + lane * 2];
        __hip_bfloat162 g3 = *(const __hip_bfloat162*)&sigb[(size_t)(p3 >> 17) * DIM + lane * 2];
        float m1 = (r > 1) ? 1.f : 0.f;
        float m2 = (r > 2) ? 1.f : 0.f;
        float m3 = (r > 3) ? 1.f : 0.f;
        ax0 += __bfloat162float(v0.x) * __bfloat162float(g0.x);
        ay0 += __bfloat162float(v0.y) * __bfloat162float(g0.y);
        ax1 += m1 * (__bfloat162float(v1.x) * __bfloat162float(g1.x));
        ay1 += m1 * (__bfloat162float(v1.y) * __bfloat162float(g1.y));
        ax0 += m2 * (__bfloat162float(v2.x) * __bfloat162float(g2.x));
        ay0 += m2 * (__bfloat162float(v2.y) * __bfloat162float(g2.y));
        ax1 += m3 * (__bfloat162float(v3.x) * __bfloat162float(g3.x));
        ay1 += m3 * (__bfloat162float(v3.y) * __bfloat162float(g3.y));
    }
    __hip_bfloat162 o;
    o.x = __float2bfloat16(ax0 + ax1);
    o.y = __float2bfloat16(ay0 + ay1);
    *(__hip_bfloat162*)&xcat_w[(size_t)wid * 256 + 128 + lane * 2] = o;
}

// ---- out_rel = rel @ W_rel^T + b_rel (fp32, tiny) ----
__global__ __launch_bounds__(128) void relout_kernel(
    const float* __restrict__ rel,
    const float* __restrict__ Wt_rel,
    const float* __restrict__ b_rel,
    float* __restrict__ out_rel) {
    __shared__ float rrow[DIM];
    int b = blockIdx.x;
    int t = threadIdx.x;
    rrow[t] = rel[(size_t)b * DIM + t];
    __syncthreads();
    float acc = b_rel[t];
    #pragma unroll 8
    for (int k = 0; k < DIM; ++k) {
        acc += rrow[k] * Wt_rel[k * DIM + t];
    }
    out_rel[(size_t)b * DIM + t] = acc;
}

// ---- out_ent = relu(xcat @ Wcat^T + bias) via bf16 MFMA, D = W·X^T operand order ----
// Output frag: col(lane&15) = x-row m, row(quad*4+reg) = out col j -> float4 stores.
// xcat aliases out: no __restrict__ on either; all loads precede all stores in
// program order and each block touches only its own 128 rows.
__global__ __launch_bounds__(256) void gemm_mfma_kernel(
    const __hip_bfloat16* xcat,                // [N][256] bf16 (aliases out)
    const __hip_bfloat16* __restrict__ Wcat,   // [128][256] bf16
    const float* __restrict__ b_self,
    const float* __restrict__ b_nei,
    float* out, int N) {
    __shared__ __hip_bfloat16 Bs[128][264];    // +8 pad; SQ_LDS_BANK_CONFLICT measured 0

    int t    = threadIdx.x;
    int wave = t >> 6;
    int lane = t & 63;
    int quad = lane >> 4;
    int r16  = lane & 15;

    // stage Wcat -> LDS: thread copies a half-row = 128 bf16 = 256 B = 16 float4
    {
        int r = t >> 1, h = t & 1;
        const float4* src = (const float4*)&Wcat[(size_t)r * 256 + h * 128];
        #pragma unroll
        for (int i = 0; i < 16; ++i) {
            *(float4*)&Bs[r][h * 128 + i * 8] = src[i];
        }
    }
    __syncthreads();

    int row0 = blockIdx.x * 128 + wave * 32;

    // x-frags (MFMA B operand): row m = row0 + mt*16 + r16, k-chunk quad*8 per k-step
    bf8 x[2][8];
    #pragma unroll
    for (int mt = 0; mt < 2; ++mt) {
        int m = row0 + mt * 16 + r16;
        if (m > N - 1) m = N - 1;               // clamp (store guarded below)
        const __hip_bfloat16* xp = &xcat[(size_t)m * 256 + quad * 8];
        #pragma unroll
        for (int ks = 0; ks < 8; ++ks) {
            x[mt][ks] = *(const bf8*)(xp + ks * 32);
        }
    }

    f4 acc[2][8];
    #pragma unroll
    for (int mt = 0; mt < 2; ++mt)
        #pragma unroll
        for (int jt = 0; jt < 8; ++jt)
            acc[mt][jt] = (f4){0.f, 0.f, 0.f, 0.f};

    #pragma unroll
    for (int ks = 0; ks < 8; ++ks) {
        #pragma unroll
        for (int jt = 0; jt < 8; ++jt) {
            bf8 w = *(const bf8*)&Bs[jt * 16 + r16][ks * 32 + quad * 8];
            acc[0][jt] = __builtin_amdgcn_mfma_f32_16x16x32_bf16(w, x[0][ks], acc[0][jt], 0, 0, 0);
            acc[1][jt] = __builtin_amdgcn_mfma_f32_16x16x32_bf16(w, x[1][ks], acc[1][jt], 0, 0, 0);
        }
    }

    // bias as float4 per jt-tile (cols jt*16 + quad*4 .. +3)
    f4 bias4[8];
    #pragma unroll
    for (int jt = 0; jt < 8; ++jt) {
        const float4 bs = *(const float4*)&b_self[jt * 16 + quad * 4];
        const float4 bn = *(const float4*)&b_nei[jt * 16 + quad * 4];
        bias4[jt] = (f4){bs.x + bn.x, bs.y + bn.y, bs.z + bn.z, bs.w + bn.w};
    }

    #pragma unroll
    for (int mt = 0; mt < 2; ++mt) {
        int m = row0 + mt * 16 + r16;
        if (m < N) {
            #pragma unroll
            for (int jt = 0; jt < 8; ++jt) {
                f4 v = acc[mt][jt] + bias4[jt];
                float4 o;
                o.x = fmaxf(v[0], 0.f);
                o.y = fmaxf(v[1], 0.f);
                o.z = fmaxf(v[2], 0.f);
                o.w = fmaxf(v[3], 0.f);
                *(float4*)&out[(size_t)m * DIM + jt * 16 + quad * 4] = o;
            }
        }
    }
}

extern "C" void kernel_launch(void* const* d_in, const int* in_sizes, int n_in,
                              void* d_out, int out_size, void* d_ws, size_t ws_size,
                              hipStream_t stream) {
    const float* ent        = (const float*)d_in[0];
    const float* rel        = (const float*)d_in[1];
    const int*   edge_index = (const int*)d_in[2];
    const int*   edge_type  = (const int*)d_in[3];
    const float* W_self     = (const float*)d_in[4];
    const float* b_self     = (const float*)d_in[5];
    const float* W_nei      = (const float*)d_in[6];
    const float* b_nei      = (const float*)d_in[7];
    const float* W_rel      = (const float*)d_in[8];
    const float* b_rel      = (const float*)d_in[9];

    const int N = in_sizes[0] / DIM;   // 100000
    const int R = in_sizes[1] / DIM;   // 500
    const int E = in_sizes[3];         // 600000

    float* out     = (float*)d_out;
    float* out_rel = out + (size_t)N * DIM;
    __hip_bfloat16* xcat = (__hip_bfloat16*)d_out;     // [N][256] bf16 in-place

    // ---- workspace layout ----
    __hip_bfloat16* sigb = (__hip_bfloat16*)d_ws;                  // R*DIM bf16
    float* Wt_rel  = (float*)(sigb + (size_t)R * DIM);             // DIM*DIM fp32
    __hip_bfloat16* Wcat = (__hip_bfloat16*)(Wt_rel + DIM * DIM);  // 128*256 bf16
    int*   offs    = (int*)(Wcat + 128 * 256);         // N+8 ints
    int*   cursor  = offs + (N + 8);                   // N+8 ints
    unsigned* spack = (unsigned*)(cursor + (N + 8));   // E u32

    const int nSig = R * DIM;
    const int sigBlocks = (nSig + 255) / 256;
    const int zeroBlocks = (N + 1 + 255) / 256;

    // 1. merged preps (sig bf16, Wcat bf16, W_rel^T, zero offs)
    prep_kernel<<<sigBlocks + 32 + 64 + zeroBlocks, 256, 0, stream>>>(
        rel, W_self, W_nei, W_rel, sigb, Wcat, Wt_rel, offs, nSig, sigBlocks, N);

    // 2. merged conv(ent->bf16) + dst histogram
    {
        int convBlocks = (int)(((long long)N * 32 + 255) / 256);
        int histBlocks = (E + 255) / 256;
        conv_hist_kernel<<<convBlocks + histBlocks, 256, 0, stream>>>(
            ent, xcat, edge_index, offs, N, E, convBlocks);
    }

    // 3. single-block scan -> offsets + cursor init
    scan_all_kernel<<<1, SCB_T, 0, stream>>>(offs, cursor, N, E);

    // 4. scatter edge ids
    scatter_ids_kernel<<<(E + 255) / 256, 256, 0, stream>>>(
        edge_index, edge_type, cursor, spack, E);

    // 5. aggregation -> xcat cols 128..255 (bf16)
    {
        long long threads = (long long)N * 64;
        aggregate_kernel<<<(int)((threads + 255) / 256), 256, 0, stream>>>(
            xcat, sigb, offs, spack, xcat, N);
    }

    // 6. out_rel
    relout_kernel<<<R, DIM, 0, stream>>>(rel, Wt_rel, b_rel, out_rel);

    // 7. fused bf16 MFMA GEMM, in-place over xcat
    {
        int blocks = (N + 127) / 128;
        gemm_mfma_kernel<<<blocks, 256, 0, stream>>>(xcat, Wcat, b_self, b_nei, out, N);
    }
}

// Round 8
// 252.638 us; speedup vs baseline: 1.8272x; 1.8272x over previous
//
#include <hip/hip_runtime.h>
#include <hip/hip_bf16.h>
#include <math.h>

#define DIM 128

typedef __bf16 bf8 __attribute__((ext_vector_type(8)));
typedef float f4 __attribute__((ext_vector_type(4)));

struct __align__(8) bf16x4 { __hip_bfloat162 a, b; };

// ---- merged prep: sigmoid(rel)->bf16, Wcat bf16, W_rel^T, zero offs ----
__global__ __launch_bounds__(256) void prep_kernel(
    const float* __restrict__ rel,
    const float* __restrict__ Ws,
    const float* __restrict__ Wn,
    const float* __restrict__ Wr,
    __hip_bfloat16* __restrict__ sigb,
    __hip_bfloat16* __restrict__ Wcat,
    float* __restrict__ Wt_rel,
    int* __restrict__ offs,
    int nSig, int sigBlocks, int N) {
    int b = blockIdx.x;
    if (b < sigBlocks) {
        int i = b * 256 + threadIdx.x;
        if (i < nSig) {
            float x = rel[i];
            sigb[i] = __float2bfloat16(1.0f / (1.0f + expf(-x)));
        }
    } else if (b < sigBlocks + 32) {
        int idx = (b - sigBlocks) * 256 + threadIdx.x;   // 0..8191, 4 elems each
        int j  = idx >> 6;
        int k0 = (idx & 63) * 4;
        const float* src = (k0 < DIM) ? &Ws[j * DIM + k0] : &Wn[j * DIM + (k0 - DIM)];
        float4 v = *(const float4*)src;
        bf16x4 o;
        o.a.x = __float2bfloat16(v.x);
        o.a.y = __float2bfloat16(v.y);
        o.b.x = __float2bfloat16(v.z);
        o.b.y = __float2bfloat16(v.w);
        *(bf16x4*)&Wcat[(size_t)j * 256 + k0] = o;
    } else if (b < sigBlocks + 32 + 64) {
        int id = (b - sigBlocks - 32) * 256 + threadIdx.x;  // 0..16383
        int k = id >> 7;
        int j = id & 127;
        Wt_rel[id] = Wr[j * DIM + k];
    } else {
        int i = (b - sigBlocks - 32 - 64) * 256 + threadIdx.x;
        if (i <= N) offs[i] = 0;
    }
}

// ---- merged: ent fp32 -> xcat bf16 (cols 0..127)  +  dst histogram ----
__global__ __launch_bounds__(256) void conv_hist_kernel(
    const float* __restrict__ ent,
    __hip_bfloat16* __restrict__ xcat,
    const int* __restrict__ edge_index,
    int* __restrict__ counts,
    int N, int E, int convBlocks) {
    if ((int)blockIdx.x < convBlocks) {
        long long tid = (long long)blockIdx.x * 256 + threadIdx.x;
        int row = (int)(tid >> 5);
        int q   = (int)(tid & 31);
        if (row >= N) return;
        float4 v = *(const float4*)&ent[(size_t)row * DIM + q * 4];
        bf16x4 o;
        o.a.x = __float2bfloat16(v.x);
        o.a.y = __float2bfloat16(v.y);
        o.b.x = __float2bfloat16(v.z);
        o.b.y = __float2bfloat16(v.w);
        *(bf16x4*)&xcat[(size_t)row * 256 + q * 4] = o;
    } else {
        int e = (blockIdx.x - convBlocks) * 256 + threadIdx.x;
        if (e < E) atomicAdd(&counts[edge_index[E + e]], 1);
    }
}

// ---- exclusive scan over N counts (3-pass, grid-wide) ----
#define SCAN_TPB 256
#define SCAN_IPT 4
#define SCAN_IPB 1024

__global__ void scan_pass1(int* __restrict__ data,
                           int* __restrict__ blockSums, int N) {
    __shared__ int ts[SCAN_TPB];
    int t = threadIdx.x;
    int base = blockIdx.x * SCAN_IPB + t * SCAN_IPT;
    int v[SCAN_IPT];
    int s = 0;
    #pragma unroll
    for (int i = 0; i < SCAN_IPT; ++i) {
        int idx = base + i;
        v[i] = (idx < N) ? data[idx] : 0;
        s += v[i];
    }
    ts[t] = s;
    __syncthreads();
    for (int off = 1; off < SCAN_TPB; off <<= 1) {
        int x = (t >= off) ? ts[t - off] : 0;
        __syncthreads();
        ts[t] += x;
        __syncthreads();
    }
    int excl = ts[t] - s;
    #pragma unroll
    for (int i = 0; i < SCAN_IPT; ++i) {
        int idx = base + i;
        if (idx < N) data[idx] = excl;
        excl += v[i];
    }
    if (t == SCAN_TPB - 1) blockSums[blockIdx.x] = ts[t];
}

// parallel exclusive scan of <=128 block sums (1 block, 128 threads)
__global__ void scan_pass2(int* __restrict__ blockSums, int nb) {
    __shared__ int s[128];
    int t = threadIdx.x;
    int v = (t < nb) ? blockSums[t] : 0;
    s[t] = v;
    __syncthreads();
    for (int off = 1; off < 128; off <<= 1) {
        int x = (t >= off) ? s[t - off] : 0;
        __syncthreads();
        s[t] += x;
        __syncthreads();
    }
    if (t < nb) blockSums[t] = s[t] - v;   // exclusive
}

__global__ void scan_pass3(int* __restrict__ offs, const int* __restrict__ blockSums,
                           int* __restrict__ cursor, int N, int E) {
    int i = blockIdx.x * blockDim.x + threadIdx.x;
    if (i < N) {
        int o = offs[i] + blockSums[i >> 10];
        offs[i] = o;
        cursor[i] = o;
    }
    if (i == 0) offs[N] = E;
}

// ---- scatter packed (src | type<<17) into CSR order ----
__global__ void scatter_ids_kernel(const int* __restrict__ edge_index,
                                   const int* __restrict__ edge_type,
                                   int* __restrict__ cursor,
                                   unsigned* __restrict__ spack, int E) {
    int e = blockIdx.x * blockDim.x + threadIdx.x;
    if (e >= E) return;
    int dst = edge_index[E + e];
    int p = atomicAdd(&cursor[dst], 1);
    spack[p] = (unsigned)edge_index[e] | ((unsigned)edge_type[e] << 17);
}

// ---- atomic-free aggregation: 1 wave / node, fully-predicated 4-wide batches ----
__global__ __launch_bounds__(256) void aggregate_kernel(
    const __hip_bfloat16* __restrict__ xcat,
    const __hip_bfloat16* __restrict__ sigb,
    const int* __restrict__ offs,
    const unsigned* __restrict__ spack,
    __hip_bfloat16* __restrict__ xcat_w, int N) {
    int wid  = (int)((blockIdx.x * (long long)blockDim.x + threadIdx.x) >> 6);
    int lane = threadIdx.x & 63;
    if (wid >= N) return;
    int beg = offs[wid], end = offs[wid + 1];
    float ax0 = 0.f, ay0 = 0.f, ax1 = 0.f, ay1 = 0.f;
    for (int e = beg; e < end; e += 4) {
        int r = end - e;                       // >= 1
        unsigned p0 = spack[e];
        unsigned p1 = spack[r > 1 ? e + 1 : e];
        unsigned p2 = spack[r > 2 ? e + 2 : e];
        unsigned p3 = spack[r > 3 ? e + 3 : e];
        __hip_bfloat162 v0 = *(const __hip_bfloat162*)&xcat[(size_t)(p0 & 0x1FFFFu) * 256 + lane * 2];
        __hip_bfloat162 v1 = *(const __hip_bfloat162*)&xcat[(size_t)(p1 & 0x1FFFFu) * 256 + lane * 2];
        __hip_bfloat162 v2 = *(const __hip_bfloat162*)&xcat[(size_t)(p2 & 0x1FFFFu) * 256 + lane * 2];
        __hip_bfloat162 v3 = *(const __hip_bfloat162*)&xcat[(size_t)(p3 & 0x1FFFFu) * 256 + lane * 2];
        __hip_bfloat162 g0 = *(const __hip_bfloat162*)&sigb[(size_t)(p0 >> 17) * DIM + lane * 2];
        __hip_bfloat162 g1 = *(const __hip_bfloat162*)&sigb[(size_t)(p1 >> 17) * DIM + lane * 2];
        __hip_bfloat162 g2 = *(const __hip_bfloat162*)&sigb[(size_t)(p2 >> 17) * DIM + lane * 2];
        __hip_bfloat162 g3 = *(const __hip_bfloat162*)&sigb[(size_t)(p3 >> 17) * DIM + lane * 2];
        float m1 = (r > 1) ? 1.f : 0.f;
        float m2 = (r > 2) ? 1.f : 0.f;
        float m3 = (r > 3) ? 1.f : 0.f;
        ax0 += __bfloat162float(v0.x) * __bfloat162float(g0.x);
        ay0 += __bfloat162float(v0.y) * __bfloat162float(g0.y);
        ax1 += m1 * (__bfloat162float(v1.x) * __bfloat162float(g1.x));
        ay1 += m1 * (__bfloat162float(v1.y) * __bfloat162float(g1.y));
        ax0 += m2 * (__bfloat162float(v2.x) * __bfloat162float(g2.x));
        ay0 += m2 * (__bfloat162float(v2.y) * __bfloat162float(g2.y));
        ax1 += m3 * (__bfloat162float(v3.x) * __bfloat162float(g3.x));
        ay1 += m3 * (__bfloat162float(v3.y) * __bfloat162float(g3.y));
    }
    __hip_bfloat162 o;
    o.x = __float2bfloat16(ax0 + ax1);
    o.y = __float2bfloat16(ay0 + ay1);
    *(__hip_bfloat162*)&xcat_w[(size_t)wid * 256 + 128 + lane * 2] = o;
}

// ---- out_rel = rel @ W_rel^T + b_rel (fp32, tiny) ----
__global__ __launch_bounds__(128) void relout_kernel(
    const float* __restrict__ rel,
    const float* __restrict__ Wt_rel,
    const float* __restrict__ b_rel,
    float* __restrict__ out_rel) {
    __shared__ float rrow[DIM];
    int b = blockIdx.x;
    int t = threadIdx.x;
    rrow[t] = rel[(size_t)b * DIM + t];
    __syncthreads();
    float acc = b_rel[t];
    #pragma unroll 8
    for (int k = 0; k < DIM; ++k) {
        acc += rrow[k] * Wt_rel[k * DIM + t];
    }
    out_rel[(size_t)b * DIM + t] = acc;
}

// ---- out_ent = relu(xcat @ Wcat^T + bias) via bf16 MFMA, D = W·X^T operand order ----
// Output frag: col(lane&15) = x-row m, row(quad*4+reg) = out col j -> float4 stores.
__global__ __launch_bounds__(256) void gemm_mfma_kernel(
    const __hip_bfloat16* xcat,                // [N][256] bf16 (aliases out)
    const __hip_bfloat16* __restrict__ Wcat,   // [128][256] bf16
    const float* __restrict__ b_self,
    const float* __restrict__ b_nei,
    float* out, int N) {
    __shared__ __hip_bfloat16 Bs[128][264];    // +8 pad; SQ_LDS_BANK_CONFLICT measured 0

    int t    = threadIdx.x;
    int wave = t >> 6;
    int lane = t & 63;
    int quad = lane >> 4;
    int r16  = lane & 15;

    // stage Wcat -> LDS: thread copies a half-row = 128 bf16 = 256 B = 16 float4
    {
        int r = t >> 1, h = t & 1;
        const float4* src = (const float4*)&Wcat[(size_t)r * 256 + h * 128];
        #pragma unroll
        for (int i = 0; i < 16; ++i) {
            *(float4*)&Bs[r][h * 128 + i * 8] = src[i];
        }
    }
    __syncthreads();

    int row0 = blockIdx.x * 128 + wave * 32;

    // x-frags (MFMA B operand): row m = row0 + mt*16 + r16, k-chunk quad*8 per k-step
    bf8 x[2][8];
    #pragma unroll
    for (int mt = 0; mt < 2; ++mt) {
        int m = row0 + mt * 16 + r16;
        if (m > N - 1) m = N - 1;               // clamp (store guarded below)
        const __hip_bfloat16* xp = &xcat[(size_t)m * 256 + quad * 8];
        #pragma unroll
        for (int ks = 0; ks < 8; ++ks) {
            x[mt][ks] = *(const bf8*)(xp + ks * 32);
        }
    }

    f4 acc[2][8];
    #pragma unroll
    for (int mt = 0; mt < 2; ++mt)
        #pragma unroll
        for (int jt = 0; jt < 8; ++jt)
            acc[mt][jt] = (f4){0.f, 0.f, 0.f, 0.f};

    #pragma unroll
    for (int ks = 0; ks < 8; ++ks) {
        #pragma unroll
        for (int jt = 0; jt < 8; ++jt) {
            bf8 w = *(const bf8*)&Bs[jt * 16 + r16][ks * 32 + quad * 8];
            acc[0][jt] = __builtin_amdgcn_mfma_f32_16x16x32_bf16(w, x[0][ks], acc[0][jt], 0, 0, 0);
            acc[1][jt] = __builtin_amdgcn_mfma_f32_16x16x32_bf16(w, x[1][ks], acc[1][jt], 0, 0, 0);
        }
    }

    // bias as float4 per jt-tile (cols jt*16 + quad*4 .. +3)
    f4 bias4[8];
    #pragma unroll
    for (int jt = 0; jt < 8; ++jt) {
        const float4 bs = *(const float4*)&b_self[jt * 16 + quad * 4];
        const float4 bn = *(const float4*)&b_nei[jt * 16 + quad * 4];
        bias4[jt] = (f4){bs.x + bn.x, bs.y + bn.y, bs.z + bn.z, bs.w + bn.w};
    }

    #pragma unroll
    for (int mt = 0; mt < 2; ++mt) {
        int m = row0 + mt * 16 + r16;
        if (m < N) {
            #pragma unroll
            for (int jt = 0; jt < 8; ++jt) {
                f4 v = acc[mt][jt] + bias4[jt];
                float4 o;
                o.x = fmaxf(v[0], 0.f);
                o.y = fmaxf(v[1], 0.f);
                o.z = fmaxf(v[2], 0.f);
                o.w = fmaxf(v[3], 0.f);
                *(float4*)&out[(size_t)m * DIM + jt * 16 + quad * 4] = o;
            }
        }
    }
}

extern "C" void kernel_launch(void* const* d_in, const int* in_sizes, int n_in,
                              void* d_out, int out_size, void* d_ws, size_t ws_size,
                              hipStream_t stream) {
    const float* ent        = (const float*)d_in[0];
    const float* rel        = (const float*)d_in[1];
    const int*   edge_index = (const int*)d_in[2];
    const int*   edge_type  = (const int*)d_in[3];
    const float* W_self     = (const float*)d_in[4];
    const float* b_self     = (const float*)d_in[5];
    const float* W_nei      = (const float*)d_in[6];
    const float* b_nei      = (const float*)d_in[7];
    const float* W_rel      = (const float*)d_in[8];
    const float* b_rel      = (const float*)d_in[9];

    const int N = in_sizes[0] / DIM;   // 100000
    const int R = in_sizes[1] / DIM;   // 500
    const int E = in_sizes[3];         // 600000

    float* out     = (float*)d_out;
    float* out_rel = out + (size_t)N * DIM;
    __hip_bfloat16* xcat = (__hip_bfloat16*)d_out;     // [N][256] bf16 in-place

    // ---- workspace layout ----
    __hip_bfloat16* sigb = (__hip_bfloat16*)d_ws;                  // R*DIM bf16
    float* Wt_rel  = (float*)(sigb + (size_t)R * DIM);             // DIM*DIM fp32
    __hip_bfloat16* Wcat = (__hip_bfloat16*)(Wt_rel + DIM * DIM);  // 128*256 bf16
    int*   offs    = (int*)(Wcat + 128 * 256);         // N+8 ints
    int*   cursor  = offs + (N + 8);                   // N+8 ints
    int*   bsums   = cursor + (N + 8);                 // 128 ints
    unsigned* spack = (unsigned*)(bsums + 128);        // E u32

    const int nSig = R * DIM;
    const int sigBlocks = (nSig + 255) / 256;
    const int zeroBlocks = (N + 1 + 255) / 256;
    const int scanBlocks = (N + SCAN_IPB - 1) / SCAN_IPB;

    // 1. merged preps (sig bf16, Wcat bf16, W_rel^T, zero offs)
    prep_kernel<<<sigBlocks + 32 + 64 + zeroBlocks, 256, 0, stream>>>(
        rel, W_self, W_nei, W_rel, sigb, Wcat, Wt_rel, offs, nSig, sigBlocks, N);

    // 2. merged conv(ent->bf16) + dst histogram
    {
        int convBlocks = (int)(((long long)N * 32 + 255) / 256);
        int histBlocks = (E + 255) / 256;
        conv_hist_kernel<<<convBlocks + histBlocks, 256, 0, stream>>>(
            ent, xcat, edge_index, offs, N, E, convBlocks);
    }

    // 3. grid-wide 3-pass scan -> offsets + cursor init
    scan_pass1<<<scanBlocks, SCAN_TPB, 0, stream>>>(offs, bsums, N);
    scan_pass2<<<1, 128, 0, stream>>>(bsums, scanBlocks);
    scan_pass3<<<(N + 255) / 256, 256, 0, stream>>>(offs, bsums, cursor, N, E);

    // 4. scatter edge ids
    scatter_ids_kernel<<<(E + 255) / 256, 256, 0, stream>>>(
        edge_index, edge_type, cursor, spack, E);

    // 5. aggregation -> xcat cols 128..255 (bf16)
    {
        long long threads = (long long)N * 64;
        aggregate_kernel<<<(int)((threads + 255) / 256), 256, 0, stream>>>(
            xcat, sigb, offs, spack, xcat, N);
    }

    // 6. out_rel
    relout_kernel<<<R, DIM, 0, stream>>>(rel, Wt_rel, b_rel, out_rel);

    // 7. fused bf16 MFMA GEMM, in-place over xcat
    {
        int blocks = (N + 127) / 128;
        gemm_mfma_kernel<<<blocks, 256, 0, stream>>>(xcat, Wcat, b_self, b_nei, out, N);
    }
}

// Round 9
// 226.532 us; speedup vs baseline: 2.0377x; 1.1152x over previous
//
#include <hip/hip_runtime.h>
#include <hip/hip_bf16.h>
#include <math.h>

#define DIM 128

typedef __bf16 bf8 __attribute__((ext_vector_type(8)));
typedef float f4 __attribute__((ext_vector_type(4)));

struct __align__(8) bf16x4 { __hip_bfloat162 a, b; };

// ---- merged prep: sigmoid(rel)->bf16, Wcat bf16, W_rel^T, zero offs ----
__global__ __launch_bounds__(256) void prep_kernel(
    const float* __restrict__ rel,
    const float* __restrict__ Ws,
    const float* __restrict__ Wn,
    const float* __restrict__ Wr,
    __hip_bfloat16* __restrict__ sigb,
    __hip_bfloat16* __restrict__ Wcat,
    float* __restrict__ Wt_rel,
    int* __restrict__ offs,
    int nSig, int sigBlocks, int N) {
    int b = blockIdx.x;
    if (b < sigBlocks) {
        int i = b * 256 + threadIdx.x;
        if (i < nSig) {
            float x = rel[i];
            sigb[i] = __float2bfloat16(1.0f / (1.0f + expf(-x)));
        }
    } else if (b < sigBlocks + 32) {
        int idx = (b - sigBlocks) * 256 + threadIdx.x;   // 0..8191, 4 elems each
        int j  = idx >> 6;
        int k0 = (idx & 63) * 4;
        const float* src = (k0 < DIM) ? &Ws[j * DIM + k0] : &Wn[j * DIM + (k0 - DIM)];
        float4 v = *(const float4*)src;
        bf16x4 o;
        o.a.x = __float2bfloat16(v.x);
        o.a.y = __float2bfloat16(v.y);
        o.b.x = __float2bfloat16(v.z);
        o.b.y = __float2bfloat16(v.w);
        *(bf16x4*)&Wcat[(size_t)j * 256 + k0] = o;
    } else if (b < sigBlocks + 32 + 64) {
        int id = (b - sigBlocks - 32) * 256 + threadIdx.x;  // 0..16383
        int k = id >> 7;
        int j = id & 127;
        Wt_rel[id] = Wr[j * DIM + k];
    } else {
        int i = (b - sigBlocks - 32 - 64) * 256 + threadIdx.x;
        if (i <= N) offs[i] = 0;
    }
}

// ---- merged: ent fp32 -> xcat bf16 (cols 0..127)  +  dst histogram w/ rank capture ----
// rank[e] = this edge's arrival order within its dst bucket; the atomic-return
// latency hides behind the concurrent BW-bound conv blocks.
__global__ __launch_bounds__(256) void conv_hist_kernel(
    const float* __restrict__ ent,
    __hip_bfloat16* __restrict__ xcat,
    const int* __restrict__ edge_index,
    int* __restrict__ counts,
    int* __restrict__ rank,
    int N, int E, int convBlocks) {
    if ((int)blockIdx.x < convBlocks) {
        long long tid = (long long)blockIdx.x * 256 + threadIdx.x;
        int row = (int)(tid >> 5);
        int q   = (int)(tid & 31);
        if (row >= N) return;
        float4 v = *(const float4*)&ent[(size_t)row * DIM + q * 4];
        bf16x4 o;
        o.a.x = __float2bfloat16(v.x);
        o.a.y = __float2bfloat16(v.y);
        o.b.x = __float2bfloat16(v.z);
        o.b.y = __float2bfloat16(v.w);
        *(bf16x4*)&xcat[(size_t)row * 256 + q * 4] = o;
    } else {
        int e = (blockIdx.x - convBlocks) * 256 + threadIdx.x;
        if (e < E) {
            rank[e] = atomicAdd(&counts[edge_index[E + e]], 1);
        }
    }
}

// ---- scan pass 1: per-1024-chunk exclusive scan, block sums out ----
#define SCAN_TPB 256
#define SCAN_IPT 4
#define SCAN_IPB 1024

__global__ void scan_pass1(int* __restrict__ data,
                           int* __restrict__ blockSums, int N) {
    __shared__ int ts[SCAN_TPB];
    int t = threadIdx.x;
    int base = blockIdx.x * SCAN_IPB + t * SCAN_IPT;
    int v[SCAN_IPT];
    int s = 0;
    #pragma unroll
    for (int i = 0; i < SCAN_IPT; ++i) {
        int idx = base + i;
        v[i] = (idx < N) ? data[idx] : 0;
        s += v[i];
    }
    ts[t] = s;
    __syncthreads();
    for (int off = 1; off < SCAN_TPB; off <<= 1) {
        int x = (t >= off) ? ts[t - off] : 0;
        __syncthreads();
        ts[t] += x;
        __syncthreads();
    }
    int excl = ts[t] - s;
    #pragma unroll
    for (int i = 0; i < SCAN_IPT; ++i) {
        int idx = base + i;
        if (idx < N) data[idx] = excl;
        excl += v[i];
    }
    if (t == SCAN_TPB - 1) blockSums[blockIdx.x] = ts[t];
}

// ---- scan finish: each block locally scans the <=128 block sums, applies ----
__global__ __launch_bounds__(256) void scan_finish_kernel(
    int* __restrict__ offs, const int* __restrict__ blockSums,
    int nb, int N, int E) {
    __shared__ int ps[128];
    __shared__ int eps[128];
    int t = threadIdx.x;
    int v = 0;
    if (t < 128) {
        v = (t < nb) ? blockSums[t] : 0;
        ps[t] = v;
    }
    __syncthreads();
    for (int off = 1; off < 128; off <<= 1) {
        int x = (t >= off && t < 128) ? ps[t - off] : 0;
        __syncthreads();
        if (t < 128) ps[t] += x;
        __syncthreads();
    }
    if (t < 128) eps[t] = ps[t] - v;   // exclusive prefix of block sums
    __syncthreads();
    int i = blockIdx.x * 256 + t;
    if (i < N)  offs[i] += eps[i >> 10];
    if (i == N) offs[N] = E;
}

// ---- scatter packed (src | type<<17): ATOMIC-FREE, p = offs[dst] + rank[e] ----
__global__ void scatter_ids_kernel(const int* __restrict__ edge_index,
                                   const int* __restrict__ edge_type,
                                   const int* __restrict__ offs,
                                   const int* __restrict__ rank,
                                   unsigned* __restrict__ spack, int E) {
    int e = blockIdx.x * blockDim.x + threadIdx.x;
    if (e >= E) return;
    int dst = edge_index[E + e];
    int p = offs[dst] + rank[e];
    spack[p] = (unsigned)edge_index[e] | ((unsigned)edge_type[e] << 17);
}

// ---- aggregation (1 wave/node, predicated 4-wide)  +  relout tail blocks ----
__global__ __launch_bounds__(256) void agg_relout_kernel(
    const __hip_bfloat16* __restrict__ xcat,
    const __hip_bfloat16* __restrict__ sigb,
    const int* __restrict__ offs,
    const unsigned* __restrict__ spack,
    __hip_bfloat16* __restrict__ xcat_w,
    const float* __restrict__ rel,
    const float* __restrict__ Wt_rel,
    const float* __restrict__ b_rel,
    float* __restrict__ out_rel,
    int N, int R, int aggBlocks) {
    if ((int)blockIdx.x < aggBlocks) {
        int wid  = (int)((blockIdx.x * (long long)256 + threadIdx.x) >> 6);
        int lane = threadIdx.x & 63;
        if (wid >= N) return;
        int beg = offs[wid], end = offs[wid + 1];
        float ax0 = 0.f, ay0 = 0.f, ax1 = 0.f, ay1 = 0.f;
        for (int e = beg; e < end; e += 4) {
            int r = end - e;                       // >= 1
            unsigned p0 = spack[e];
            unsigned p1 = spack[r > 1 ? e + 1 : e];
            unsigned p2 = spack[r > 2 ? e + 2 : e];
            unsigned p3 = spack[r > 3 ? e + 3 : e];
            __hip_bfloat162 v0 = *(const __hip_bfloat162*)&xcat[(size_t)(p0 & 0x1FFFFu) * 256 + lane * 2];
            __hip_bfloat162 v1 = *(const __hip_bfloat162*)&xcat[(size_t)(p1 & 0x1FFFFu) * 256 + lane * 2];
            __hip_bfloat162 v2 = *(const __hip_bfloat162*)&xcat[(size_t)(p2 & 0x1FFFFu) * 256 + lane * 2];
            __hip_bfloat162 v3 = *(const __hip_bfloat162*)&xcat[(size_t)(p3 & 0x1FFFFu) * 256 + lane * 2];
            __hip_bfloat162 g0 = *(const __hip_bfloat162*)&sigb[(size_t)(p0 >> 17) * DIM + lane * 2];
            __hip_bfloat162 g1 = *(const __hip_bfloat162*)&sigb[(size_t)(p1 >> 17) * DIM + lane * 2];
            __hip_bfloat162 g2 = *(const __hip_bfloat162*)&sigb[(size_t)(p2 >> 17) * DIM + lane * 2];
            __hip_bfloat162 g3 = *(const __hip_bfloat162*)&sigb[(size_t)(p3 >> 17) * DIM + lane * 2];
            float m1 = (r > 1) ? 1.f : 0.f;
            float m2 = (r > 2) ? 1.f : 0.f;
            float m3 = (r > 3) ? 1.f : 0.f;
            ax0 += __bfloat162float(v0.x) * __bfloat162float(g0.x);
            ay0 += __bfloat162float(v0.y) * __bfloat162float(g0.y);
            ax1 += m1 * (__bfloat162float(v1.x) * __bfloat162float(g1.x));
            ay1 += m1 * (__bfloat162float(v1.y) * __bfloat162float(g1.y));
            ax0 += m2 * (__bfloat162float(v2.x) * __bfloat162float(g2.x));
            ay0 += m2 * (__bfloat162float(v2.y) * __bfloat162float(g2.y));
            ax1 += m3 * (__bfloat162float(v3.x) * __bfloat162float(g3.x));
            ay1 += m3 * (__bfloat162float(v3.y) * __bfloat162float(g3.y));
        }
        __hip_bfloat162 o;
        o.x = __float2bfloat16(ax0 + ax1);
        o.y = __float2bfloat16(ay0 + ay1);
        *(__hip_bfloat162*)&xcat_w[(size_t)wid * 256 + 128 + lane * 2] = o;
    } else {
        // relout: 2 rel rows per block
        __shared__ float rr[2][DIM];
        int idx  = blockIdx.x - aggBlocks;     // 0 .. R/2-1
        int half = threadIdx.x >> 7;           // 0 or 1
        int col  = threadIdx.x & 127;
        int row  = idx * 2 + half;
        if (row < R) rr[half][col] = rel[(size_t)row * DIM + col];
        __syncthreads();
        if (row >= R) return;
        float acc = b_rel[col];
        #pragma unroll 8
        for (int k = 0; k < DIM; ++k) {
            acc += rr[half][k] * Wt_rel[k * DIM + col];
        }
        out_rel[(size_t)row * DIM + col] = acc;
    }
}

// ---- out_ent = relu(xcat @ Wcat^T + bias) via bf16 MFMA, D = W·X^T order ----
__global__ __launch_bounds__(256) void gemm_mfma_kernel(
    const __hip_bfloat16* xcat,                // [N][256] bf16 (aliases out)
    const __hip_bfloat16* __restrict__ Wcat,   // [128][256] bf16
    const float* __restrict__ b_self,
    const float* __restrict__ b_nei,
    float* out, int N) {
    __shared__ __hip_bfloat16 Bs[128][264];    // +8 pad; SQ_LDS_BANK_CONFLICT measured 0

    int t    = threadIdx.x;
    int wave = t >> 6;
    int lane = t & 63;
    int quad = lane >> 4;
    int r16  = lane & 15;

    {
        int r = t >> 1, h = t & 1;
        const float4* src = (const float4*)&Wcat[(size_t)r * 256 + h * 128];
        #pragma unroll
        for (int i = 0; i < 16; ++i) {
            *(float4*)&Bs[r][h * 128 + i * 8] = src[i];
        }
    }
    __syncthreads();

    int row0 = blockIdx.x * 128 + wave * 32;

    bf8 x[2][8];
    #pragma unroll
    for (int mt = 0; mt < 2; ++mt) {
        int m = row0 + mt * 16 + r16;
        if (m > N - 1) m = N - 1;               // clamp (store guarded below)
        const __hip_bfloat16* xp = &xcat[(size_t)m * 256 + quad * 8];
        #pragma unroll
        for (int ks = 0; ks < 8; ++ks) {
            x[mt][ks] = *(const bf8*)(xp + ks * 32);
        }
    }

    f4 acc[2][8];
    #pragma unroll
    for (int mt = 0; mt < 2; ++mt)
        #pragma unroll
        for (int jt = 0; jt < 8; ++jt)
            acc[mt][jt] = (f4){0.f, 0.f, 0.f, 0.f};

    #pragma unroll
    for (int ks = 0; ks < 8; ++ks) {
        #pragma unroll
        for (int jt = 0; jt < 8; ++jt) {
            bf8 w = *(const bf8*)&Bs[jt * 16 + r16][ks * 32 + quad * 8];
            acc[0][jt] = __builtin_amdgcn_mfma_f32_16x16x32_bf16(w, x[0][ks], acc[0][jt], 0, 0, 0);
            acc[1][jt] = __builtin_amdgcn_mfma_f32_16x16x32_bf16(w, x[1][ks], acc[1][jt], 0, 0, 0);
        }
    }

    f4 bias4[8];
    #pragma unroll
    for (int jt = 0; jt < 8; ++jt) {
        const float4 bs = *(const float4*)&b_self[jt * 16 + quad * 4];
        const float4 bn = *(const float4*)&b_nei[jt * 16 + quad * 4];
        bias4[jt] = (f4){bs.x + bn.x, bs.y + bn.y, bs.z + bn.z, bs.w + bn.w};
    }

    #pragma unroll
    for (int mt = 0; mt < 2; ++mt) {
        int m = row0 + mt * 16 + r16;
        if (m < N) {
            #pragma unroll
            for (int jt = 0; jt < 8; ++jt) {
                f4 v = acc[mt][jt] + bias4[jt];
                float4 o;
                o.x = fmaxf(v[0], 0.f);
                o.y = fmaxf(v[1], 0.f);
                o.z = fmaxf(v[2], 0.f);
                o.w = fmaxf(v[3], 0.f);
                *(float4*)&out[(size_t)m * DIM + jt * 16 + quad * 4] = o;
            }
        }
    }
}

extern "C" void kernel_launch(void* const* d_in, const int* in_sizes, int n_in,
                              void* d_out, int out_size, void* d_ws, size_t ws_size,
                              hipStream_t stream) {
    const float* ent        = (const float*)d_in[0];
    const float* rel        = (const float*)d_in[1];
    const int*   edge_index = (const int*)d_in[2];
    const int*   edge_type  = (const int*)d_in[3];
    const float* W_self     = (const float*)d_in[4];
    const float* b_self     = (const float*)d_in[5];
    const float* W_nei      = (const float*)d_in[6];
    const float* b_nei      = (const float*)d_in[7];
    const float* W_rel      = (const float*)d_in[8];
    const float* b_rel      = (const float*)d_in[9];

    const int N = in_sizes[0] / DIM;   // 100000
    const int R = in_sizes[1] / DIM;   // 500
    const int E = in_sizes[3];         // 600000

    float* out     = (float*)d_out;
    float* out_rel = out + (size_t)N * DIM;
    __hip_bfloat16* xcat = (__hip_bfloat16*)d_out;     // [N][256] bf16 in-place

    // ---- workspace layout ----
    __hip_bfloat16* sigb = (__hip_bfloat16*)d_ws;                  // R*DIM bf16
    float* Wt_rel  = (float*)(sigb + (size_t)R * DIM);             // DIM*DIM fp32
    __hip_bfloat16* Wcat = (__hip_bfloat16*)(Wt_rel + DIM * DIM);  // 128*256 bf16
    int*   offs    = (int*)(Wcat + 128 * 256);         // N+8 ints
    int*   bsums   = offs + (N + 8);                   // 128 ints
    int*   rank    = bsums + 128;                      // E ints
    unsigned* spack = (unsigned*)(rank + E);           // E u32

    const int nSig = R * DIM;
    const int sigBlocks = (nSig + 255) / 256;
    const int zeroBlocks = (N + 1 + 255) / 256;
    const int scanBlocks = (N + SCAN_IPB - 1) / SCAN_IPB;   // 98 <= 128

    // 1. merged preps (sig bf16, Wcat bf16, W_rel^T, zero offs)
    prep_kernel<<<sigBlocks + 32 + 64 + zeroBlocks, 256, 0, stream>>>(
        rel, W_self, W_nei, W_rel, sigb, Wcat, Wt_rel, offs, nSig, sigBlocks, N);

    // 2. merged conv(ent->bf16) + dst histogram with rank capture
    {
        int convBlocks = (int)(((long long)N * 32 + 255) / 256);
        int histBlocks = (E + 255) / 256;
        conv_hist_kernel<<<convBlocks + histBlocks, 256, 0, stream>>>(
            ent, xcat, edge_index, offs, rank, N, E, convBlocks);
    }

    // 3. two-pass scan -> offsets
    scan_pass1<<<scanBlocks, SCAN_TPB, 0, stream>>>(offs, bsums, N);
    scan_finish_kernel<<<(N + 1 + 255) / 256, 256, 0, stream>>>(
        offs, bsums, scanBlocks, N, E);

    // 4. atomic-free scatter of edge ids
    scatter_ids_kernel<<<(E + 255) / 256, 256, 0, stream>>>(
        edge_index, edge_type, offs, rank, spack, E);

    // 5. aggregation -> xcat cols 128..255  +  relout tail blocks
    {
        int aggBlocks = (int)(((long long)N * 64 + 255) / 256);
        int relBlocks = (R + 1) / 2;
        agg_relout_kernel<<<aggBlocks + relBlocks, 256, 0, stream>>>(
            xcat, sigb, offs, spack, xcat, rel, Wt_rel, b_rel, out_rel,
            N, R, aggBlocks);
    }

    // 6. fused bf16 MFMA GEMM, in-place over xcat
    {
        int blocks = (N + 127) / 128;
        gemm_mfma_kernel<<<blocks, 256, 0, stream>>>(xcat, Wcat, b_self, b_nei, out, N);
    }
}